// Round 2
// baseline (126.298 us; speedup 1.0000x reference)
//
#include <hip/hip_runtime.h>

// Static shapes: B=16, T=512, D=384 (=96 float4), F=max_len=4096.
#define BB    16
#define TT    512
#define FF    4096
#define DD4   96                 // float4 per row
#define NTHR  256
#define FPB   64                 // frames per block
#define CHUNKS (FF / FPB)        // 64 chunks per batch
#define NBLK  (BB * CHUNKS)      // 1024 blocks
#define NXCD  8

typedef float f4 __attribute__((ext_vector_type(4)));

// Single fused kernel. Per block:
//  1. load 512 durations for its batch (int2 per thread, L2-broadcast),
//  2. shfl wave-scan + LDS cross-wave fixup -> cum[512] in LDS,
//  3. per frame: branchless binary search (== jnp.searchsorted side="right",
//     so zero-duration phonemes are skipped exactly like the reference),
//  4. gather 64 frames x 384 floats with float4 loads + NT stores.
// Eliminates the build_idx dispatch, the inter-kernel drain, and the
// fidx global round-trip.
__global__ __launch_bounds__(NTHR) void lenreg_kernel(
    const f4* __restrict__ x, const int* __restrict__ dur,
    f4* __restrict__ out) {

    int bid = blockIdx.x;
    // bijective XCD swizzle (1024 % 8 == 0): XCD k owns batches 2k,2k+1
    bid = (bid & (NXCD - 1)) * (NBLK / NXCD) + (bid >> 3);

    const int b     = bid >> 6;          // bid / CHUNKS
    const int chunk = bid & (CHUNKS - 1);
    const int t     = threadIdx.x;
    const int lane  = t & 63;
    const int wid   = t >> 6;

    __shared__ int s_cum[TT];
    __shared__ int s_ws[NTHR / 64];

    // ---- scan: each thread owns durations 2t, 2t+1 ----
    const int2 dd = ((const int2*)(dur + b * TT))[t];
    int v = dd.x + dd.y;
#pragma unroll
    for (int off = 1; off < 64; off <<= 1) {
        int u = __shfl_up(v, off, 64);
        if (lane >= off) v += u;
    }
    if (lane == 63) s_ws[wid] = v;
    __syncthreads();
    int base = 0;
#pragma unroll
    for (int w = 0; w < NTHR / 64 - 1; ++w)
        if (w < wid) base += s_ws[w];
    const int c1 = base + v;             // inclusive cum[2t+1]
    s_cum[2 * t]     = c1 - dd.y;        // inclusive cum[2t]
    s_cum[2 * t + 1] = c1;
    __syncthreads();

    const int total = s_cum[TT - 1];     // <= 512*7 = 3584 < 4096
    const int fl    = t >> 4;            // frame-in-tile 0..15
    const int c0    = t & 15;            // column group
    const int fbase = chunk * FPB;

    // ---- 4 binary searches up front (independent -> ILP hides LDS latency)
    // idx = #{ j : cum[j] <= f }  ==  searchsorted(cum, f, side="right")
    int idx0, idx1, idx2, idx3;
    {
        int ii[4];
#pragma unroll
        for (int it = 0; it < 4; ++it) {
            const int f = fbase + it * 16 + fl;
            int idx = 0;
#pragma unroll
            for (int step = 256; step > 0; step >>= 1) {
                if (idx + step <= TT && s_cum[idx + step - 1] <= f) idx += step;
            }
            ii[it] = idx;
        }
        idx0 = ii[0]; idx1 = ii[1]; idx2 = ii[2]; idx3 = ii[3];
    }

    // ---- gather: 4 iterations of the proven 16-frame x 16-column pattern
#pragma unroll
    for (int it = 0; it < 4; ++it) {
        const int idx = (it == 0) ? idx0 : (it == 1) ? idx1 : (it == 2) ? idx2 : idx3;
        const int f   = fbase + it * 16 + fl;
        f4* dst = out + ((size_t)b * FF + f) * DD4;
        if (f < total) {
            const f4* src = x + ((size_t)b * TT + idx) * DD4;
#pragma unroll
            for (int k = 0; k < 6; ++k)
                __builtin_nontemporal_store(src[c0 + 16 * k], &dst[c0 + 16 * k]);
        } else {
            const f4 z = {0.f, 0.f, 0.f, 0.f};
#pragma unroll
            for (int k = 0; k < 6; ++k)
                __builtin_nontemporal_store(z, &dst[c0 + 16 * k]);
        }
    }
}

extern "C" void kernel_launch(void* const* d_in, const int* in_sizes, int n_in,
                              void* d_out, int out_size, void* d_ws, size_t ws_size,
                              hipStream_t stream) {
    const float* x = (const float*)d_in[0];
    const int* dur = (const int*)d_in[1];   // int32 on device
    (void)d_ws; (void)ws_size;

    lenreg_kernel<<<NBLK, NTHR, 0, stream>>>(
        (const f4*)x, dur, (f4*)d_out);
}

// Round 4
// 125.317 us; speedup vs baseline: 1.0078x; 1.0078x over previous
//
#include <hip/hip_runtime.h>

// Static shapes: B=16, T=512, D=384 (=96 float4), F=max_len=4096.
#define BB    16
#define TT    512
#define FF    4096
#define DD4   96                 // float4 per row
#define NTHR  256
#define FPB   64                 // frames per block
#define CHUNKS (FF / FPB)        // 64 chunks per batch
#define NBLK  (BB * CHUNKS)      // 1024 blocks
#define PPB   (FPB * DD4)        // 6144 float4 per block chunk
#define NXCD  8

typedef float f4 __attribute__((ext_vector_type(4)));

// Fused kernel, byte-linear store phase.
//  1. scan durations (shfl + LDS fixup) -> cum[512] in LDS
//  2. one binary search per FRAME (64 searches/block) -> s_idx[64] in LDS
//     (searchsorted side="right" + clamp, exactly the reference semantics)
//  3. store phase: thread t writes float4 elements p = t + 256k of the
//     block's contiguous 6144-float4 output chunk. Every wave-level store
//     is 64 consecutive float4 = 1024 B linear -- identical pattern to the
//     6.3 TB/s fill. frame = p/96, col = p%96 (compiler magic-div);
//     idx broadcast from LDS (<=2 distinct frames per wave).
__global__ __launch_bounds__(NTHR) void lenreg_kernel(
    const f4* __restrict__ x, const int* __restrict__ dur,
    f4* __restrict__ out) {

    int bid = blockIdx.x;
    // bijective XCD swizzle (1024 % 8 == 0)
    bid = (bid & (NXCD - 1)) * (NBLK / NXCD) + (bid >> 3);

    const int b     = bid >> 6;          // bid / CHUNKS
    const int chunk = bid & (CHUNKS - 1);
    const int t     = threadIdx.x;
    const int lane  = t & 63;
    const int wid   = t >> 6;

    __shared__ int s_cum[TT];
    __shared__ int s_ws[NTHR / 64];
    __shared__ int s_idx[FPB];

    // ---- scan: each thread owns durations 2t, 2t+1 ----
    const int2 dd = ((const int2*)(dur + b * TT))[t];
    int v = dd.x + dd.y;
#pragma unroll
    for (int off = 1; off < 64; off <<= 1) {
        int u = __shfl_up(v, off, 64);
        if (lane >= off) v += u;
    }
    if (lane == 63) s_ws[wid] = v;
    __syncthreads();
    int base = 0;
#pragma unroll
    for (int w = 0; w < NTHR / 64 - 1; ++w)
        if (w < wid) base += s_ws[w];
    const int c1 = base + v;             // inclusive cum[2t+1]
    s_cum[2 * t]     = c1 - dd.y;        // inclusive cum[2t]
    s_cum[2 * t + 1] = c1;
    __syncthreads();

    const int total = s_cum[TT - 1];     // <= 512*7 = 3584 < 4096
    const int fbase = chunk * FPB;

    // ---- one search per frame of this chunk (wave 0 does all 64) ----
    if (t < FPB) {
        const int f = fbase + t;
        int idx = 0;
#pragma unroll
        for (int step = 256; step > 0; step >>= 1)
            if (idx + step <= TT && s_cum[idx + step - 1] <= f) idx += step;
        s_idx[t] = idx < TT - 1 ? idx : TT - 1;   // reference's clamp
    }
    __syncthreads();

    // ---- byte-linear store phase ----
    const f4* xb = x + (size_t)b * TT * DD4;
    f4* ob = out + (size_t)(b * FF + fbase) * DD4;
#pragma unroll
    for (int k = 0; k < PPB / NTHR; ++k) {       // 24 iterations
        const int p = t + NTHR * k;              // 0..6143
        const int f = p / DD4;                   // magic-div by 96
        const int c = p - f * DD4;
        f4 val = {0.f, 0.f, 0.f, 0.f};
        if (fbase + f < total) val = xb[s_idx[f] * DD4 + c];
        ob[p] = val;
    }
}

extern "C" void kernel_launch(void* const* d_in, const int* in_sizes, int n_in,
                              void* d_out, int out_size, void* d_ws, size_t ws_size,
                              hipStream_t stream) {
    const float* x = (const float*)d_in[0];
    const int* dur = (const int*)d_in[1];   // int32 on device
    (void)d_ws; (void)ws_size;

    lenreg_kernel<<<NBLK, NTHR, 0, stream>>>(
        (const f4*)x, dur, (f4*)d_out);
}